// Round 5
// baseline (234.288 us; speedup 1.0000x reference)
//
#include <hip/hip_runtime.h>

// Problem constants
#define NTOK 65536          // B*S tokens
#define DDIM 64             // embedding dim
#define KCB  4096           // codebook size
#define MB   64             // tokens per block (grid 1024; codebook read ONCE per block)
#define NTILES 256          // 16-col tiles in codebook
#define TPW  32             // tiles per wave (8 waves x 32 tiles = 256 tiles)
#define LCAP 6144           // candidate capacity (expect ~1000/block with fixed thr)
#define WWIN 5.0e-4f        // >= 2*delta; delta <= 2.2e-4 (single-product worst case)
#define IDXOFF  (NTOK * DDIM)
#define LOSSOFF (NTOK * DDIM + NTOK)

typedef __bf16 bf16x8 __attribute__((ext_vector_type(8)));
typedef float  f32x4  __attribute__((ext_vector_type(4)));

__device__ __forceinline__ float opaque(float x) { asm volatile("" : "+v"(x)); return x; }

// numpy pairwise sum of squares, n=64 (array form, used by k_prep)
__device__ __forceinline__ float np_sumsq64(const float* __restrict__ v) {
    float r[8];
#pragma unroll
    for (int j = 0; j < 8; ++j) r[j] = opaque(v[j] * v[j]);
#pragma unroll
    for (int i = 1; i < 8; ++i)
#pragma unroll
        for (int j = 0; j < 8; ++j) r[j] += opaque(v[8 * i + j] * v[8 * i + j]);
    return ((r[0] + r[1]) + (r[2] + r[3])) + ((r[4] + r[5]) + (r[6] + r[7]));
}

__device__ __forceinline__ unsigned short bf16rne(float x) {
    unsigned u = __float_as_uint(x);
    return (unsigned short)((u + 0x7fffu + ((u >> 16) & 1u)) >> 16);
}

// ---- Prep: exact e2 (np pairwise) + fragment-packed bf16(high) codebook ----
// pfh[tile*128 + kh*64 + lane]: lane = quad*16+l15 holds
//   bf16(e_row[tile*16+l15][quad*8 + kh*32 .. +8])  (16 B = 8 bf16)
__global__ void k_prep(const float* __restrict__ emb, float* __restrict__ e2,
                       uint4* __restrict__ pfh, double* __restrict__ lossacc) {
    int k = blockIdx.x * blockDim.x + threadIdx.x;
    if (k == 0) *lossacc = 0.0;
    if (k >= KCB) return;
    float row[DDIM];
    const float4* r4 = (const float4*)(emb + (size_t)k * DDIM);
#pragma unroll
    for (int i = 0; i < DDIM / 4; ++i) {
        float4 v = r4[i];
        row[4*i+0] = v.x; row[4*i+1] = v.y; row[4*i+2] = v.z; row[4*i+3] = v.w;
    }
    e2[k] = np_sumsq64(row);
    const int tile = k >> 4, rr = k & 15;
#pragma unroll
    for (int q = 0; q < 4; ++q) {
#pragma unroll
        for (int kh = 0; kh < 2; ++kh) {
            union { uint4 v; unsigned short s[8]; } th;
#pragma unroll
            for (int j = 0; j < 8; ++j) th.s[j] = bf16rne(row[q*8 + kh*32 + j]);
            pfh[(size_t)tile * 128 + kh * 64 + q * 16 + rr] = th.v;
        }
    }
}

// ---- Main: fixed-threshold MFMA sweep, branchless capture, exact rescore ----
// 512 thr = 8 waves; wave wn covers a 32-tile eighth for ALL 64 block tokens
// (ms 0..3). Codebook read once per block (round-0 traffic) with 32 waves/CU
// supply. No waves-per-eu hint: rounds 1-3 showed the allocator targets a
// 256-reg budget under (N,k) hints (spilling at k=8, 64 regs at k=4) while
// residency pinned at ~12 waves/CU; this build tests the uncapped path.
// Inner loop is branch-free: thr[] is FIXED after one preview commit (a fixed,
// looser thr only ADDS candidates -> still a correct superset, ~1000 vs LCAP
// 6144); per-h work = cmp + mask-bit (no fminf/add), ONE ballot branch per
// tile, rare bit-scan append. All in-loop commit_reloads (576 ds_swizzle/wave)
// deleted. Exact rescore: s = fl(fl(z2+e2)-seqFMA(2z*e)) -> lex (s,n).
__global__ __launch_bounds__(512)
void k_vq(const float* __restrict__ z, const float* __restrict__ emb,
          const float* __restrict__ e2g, const uint4* __restrict__ pfh,
          float* __restrict__ out, double* __restrict__ lossacc) {
    __shared__ float z2s[MB];
    __shared__ unsigned v0u[MB];
    __shared__ unsigned long long keys[MB];
    __shared__ unsigned list[LCAP];          // 24 KB
    __shared__ int lcnt;
    __shared__ float red[512];
    __shared__ int bidx_s[MB];

    const int tid  = threadIdx.x;
    const int lane = tid & 63;
    const int l15  = lane & 15;
    const int quad = lane >> 4;
    const int wn   = tid >> 6;   // 0..7 : 32-tile eighth
    const int tok0 = blockIdx.x * MB;
    const size_t zbase = (size_t)tok0 * DDIM;

    if (tid < MB) { v0u[tid] = 0x7f800000u; keys[tid] = 0xFFFFFFFFFFFFFFFFull; }
    if (tid == 0) lcnt = 0;

    // ---- A-fragments: bf16(-2z), global -> VGPRs (whole-kernel live) ----
    bf16x8 Ah[4][2];   // [ms][kh] — 32 VGPRs
#pragma unroll
    for (int ms = 0; ms < 4; ++ms) {
        const float* p = z + zbase + (size_t)(ms * 16 + l15) * DDIM + quad * 8;
#pragma unroll
        for (int kh = 0; kh < 2; ++kh) {
            float4 u0 = *(const float4*)(p + kh * 32);
            float4 u1 = *(const float4*)(p + kh * 32 + 4);
            float d[8] = {-(u0.x + u0.x), -(u0.y + u0.y), -(u0.z + u0.z), -(u0.w + u0.w),
                          -(u1.x + u1.x), -(u1.y + u1.y), -(u1.z + u1.z), -(u1.w + u1.w)};
            union { bf16x8 v; unsigned short u[8]; } th;
#pragma unroll
            for (int j = 0; j < 8; ++j) th.u[j] = bf16rne(d[j]);
            Ah[ms][kh] = th.v;
        }
    }

    // z2 per token — streamed np pairwise (same FP sequence as np_sumsq64,
    // but only ~16 live regs instead of 64+8)
    if (tid < MB) {
        const float4* zr4 = (const float4*)(z + zbase + (size_t)tid * DDIM);
        float r8[8];
#pragma unroll
        for (int i = 0; i < 8; ++i) {
            float4 v0 = zr4[2 * i], v1 = zr4[2 * i + 1];
            float c[8] = {v0.x, v0.y, v0.z, v0.w, v1.x, v1.y, v1.z, v1.w};
            if (i == 0) {
#pragma unroll
                for (int j = 0; j < 8; ++j) r8[j] = opaque(c[j] * c[j]);
            } else {
#pragma unroll
                for (int j = 0; j < 8; ++j) r8[j] += opaque(c[j] * c[j]);
            }
        }
        z2s[tid] = ((r8[0] + r8[1]) + (r8[2] + r8[3])) + ((r8[4] + r8[5]) + (r8[6] + r8[7]));
    }

    const uint4* pbase = pfh + (size_t)(wn * TPW) * 128 + lane;
    const int ncbase = (wn * TPW) * 16 + l15;

    // ---- preview (4 tiles/wave, 8 waves -> 512-code seed), raw running min --
    float rm[16];
#pragma unroll
    for (int i = 0; i < 16; ++i) rm[i] = 3.0e38f;
#pragma unroll 1
    for (int t = 0; t < 4; ++t) {
        union { uint4 q; bf16x8 v; } b0, b1;
        b0.q = pbase[(size_t)t * 128]; b1.q = pbase[(size_t)t * 128 + 64];
#pragma unroll
        for (int ms = 0; ms < 4; ++ms) {
            f32x4 a = {0.5f, 0.5f, 0.5f, 0.5f};
            a = __builtin_amdgcn_mfma_f32_16x16x32_bf16(Ah[ms][0], b0.v, a, 0, 0, 0);
            a = __builtin_amdgcn_mfma_f32_16x16x32_bf16(Ah[ms][1], b1.v, a, 0, 0, 0);
#pragma unroll
            for (int r = 0; r < 4; ++r) rm[ms * 4 + r] = fminf(rm[ms * 4 + r], a[r]);
        }
    }
    // commit raw mins (16-lane group reduce -> block atomicMin), barrier, load
#pragma unroll
    for (int i = 0; i < 16; ++i) {
        float v = rm[i];
        v = fminf(v, __shfl_xor(v, 1));
        v = fminf(v, __shfl_xor(v, 2));
        v = fminf(v, __shfl_xor(v, 4));
        v = fminf(v, __shfl_xor(v, 8));
        if (l15 == 0)
            atomicMin(&v0u[(i >> 2) * 16 + quad * 4 + (i & 3)], __float_as_uint(v));
    }
    __syncthreads();   // also covers z2s/lcnt init

    float thr[16];     // FIXED for the whole sweep: block 512-code min + W
#pragma unroll
    for (int i = 0; i < 16; ++i)
        thr[i] = __uint_as_float(v0u[(i >> 2) * 16 + quad * 4 + (i & 3)]) + WWIN;

    // ---- main sweep: branch-free capture, depth-2 prefetch, no barriers ----
    auto sweep_tile = [&](uint4 q0, uint4 q1, int t) {
        union { uint4 q; bf16x8 v; } b0, b1;
        b0.q = q0; b1.q = q1;
        unsigned mask = 0;
#pragma unroll
        for (int ms = 0; ms < 4; ++ms) {
            f32x4 a = {0.5f, 0.5f, 0.5f, 0.5f};
            a = __builtin_amdgcn_mfma_f32_16x16x32_bf16(Ah[ms][0], b0.v, a, 0, 0, 0);
            a = __builtin_amdgcn_mfma_f32_16x16x32_bf16(Ah[ms][1], b1.v, a, 0, 0, 0);
#pragma unroll
            for (int r = 0; r < 4; ++r)
                mask |= (a[r] <= thr[ms * 4 + r]) ? (1u << (ms * 4 + r)) : 0u;
        }
        if (__ballot(mask != 0)) {          // ~1 branch per tile; usually cheap
            const int ncol = ncbase + t * 16;
            while (mask) {
                int b = __builtin_ctz(mask);
                mask &= mask - 1;
                int m = (b >> 2) * 16 + quad * 4 + (b & 3);
                int idx = atomicAdd(&lcnt, 1);
                if (idx < LCAP)
                    list[idx] = ((unsigned)m << 12) | (unsigned)ncol;
            }
        }
    };

    uint4 a0 = pbase[0],   a1 = pbase[64];
    uint4 b0 = pbase[128], b1 = pbase[192];
    const uint4* pf = pbase + 256;
#pragma unroll 1
    for (int t = 0; t < TPW; t += 2) {
        uint4 c0 = a0, c1 = a1, d0 = b0, d1 = b1;
        if (t + 2 < TPW) {
            c0 = pf[0]; c1 = pf[64]; d0 = pf[128]; d1 = pf[192];
            pf += 256;
        }
        sweep_tile(a0, a1, t);
        sweep_tile(b0, b1, t + 1);
        a0 = c0; a1 = c1; b0 = d0; b1 = d1;
    }
    __syncthreads();   // list complete & visible

    // ---- Exact rescore (np chain), lexicographic (s, n) min per token ----
    int cnt = lcnt; if (cnt > LCAP) cnt = LCAP;
    for (int i = tid; i < cnt; i += 512) {
        unsigned e = list[i];
        int m = (int)(e >> 12), n = (int)(e & 4095u);
        const float* zrow = z + zbase + (size_t)m * DDIM;
        const float* erow = emb + (size_t)n * DDIM;
        float a = 0.f;
#pragma unroll
        for (int j = 0; j < DDIM; ++j) a = fmaf(zrow[j] + zrow[j], erow[j], a);
        float s = (z2s[m] + e2g[n]) - a;   // two fp32 roundings, exactly as np
        unsigned long long key = ((unsigned long long)__float_as_uint(s) << 32)
                               | (unsigned long long)(unsigned)n;
        atomicMin(&keys[m], key);
    }
    __syncthreads();

    if (tid < MB) {
        int nstar = (int)(keys[tid] & 0xffffffffULL);
        bidx_s[tid] = nstar;
        out[IDXOFF + tok0 + tid] = (float)nstar;
    }
    __syncthreads();

    // ---- Epilogue: quantized gather-write (coalesced float4) + loss ----
    float lsum = 0.f;
#pragma unroll
    for (int it = 0; it < 2; ++it) {
        int f  = it * 512 + tid;    // 0..1023 float4 slots (64 tok * 16)
        int tt = f >> 4, cc = f & 15;
        int idx = bidx_s[tt];
        float4 qv = ((const float4*)(emb + (size_t)idx * DDIM))[cc];
        float4 zv = ((const float4*)(z + zbase))[f];
        ((float4*)(out + zbase))[f] = qv;
        float dx = qv.x - zv.x, dy = qv.y - zv.y;
        float dz = qv.z - zv.z, dw = qv.w - zv.w;
        lsum += dx * dx + dy * dy + dz * dz + dw * dw;
    }
    red[tid] = lsum;
    __syncthreads();
    for (int s = 256; s > 0; s >>= 1) {
        if (tid < s) red[tid] += red[tid + s];
        __syncthreads();
    }
    if (tid == 0) atomicAdd(lossacc, (double)red[0]);
}

__global__ void k_fin(const double* __restrict__ lossacc, float* __restrict__ out) {
    out[LOSSOFF] = (float)(2.0 * (*lossacc) / (double)(NTOK * DDIM));
}

extern "C" void kernel_launch(void* const* d_in, const int* in_sizes, int n_in,
                              void* d_out, int out_size, void* d_ws, size_t ws_size,
                              hipStream_t stream) {
    const float* z   = (const float*)d_in[0];   // [16,4096,64] fp32
    const float* emb = (const float*)d_in[1];   // [4096,64] fp32
    float* out = (float*)d_out;

    char* ws = (char*)d_ws;
    float*  e2g     = (float*)(ws);                 // 16 KB
    uint4*  pfh     = (uint4*)(ws + 16384);         // 512 KB packed high frags
    double* lossacc = (double*)(ws + 16384 + 524288);

    hipLaunchKernelGGL(k_prep, dim3(64), dim3(64), 0, stream, emb, e2g, pfh, lossacc);
    hipLaunchKernelGGL(k_vq, dim3(NTOK / MB), dim3(512), 0, stream,
                       z, emb, e2g, pfh, out, lossacc);
    hipLaunchKernelGGL(k_fin, dim3(1), dim3(1), 0, stream, lossacc, out);
}

// Round 6
// 171.547 us; speedup vs baseline: 1.3657x; 1.3657x over previous
//
#include <hip/hip_runtime.h>

// Problem constants
#define NTOK 65536          // B*S tokens
#define DDIM 64             // embedding dim
#define KCB  4096           // codebook size
#define MB   64             // tokens per block
#define NTILES 256          // 16-col tiles in codebook
#define TPW  64             // tiles per wave (wn quarter: 1024 codes)
#define LCAP 4096           // candidate capacity (~500/block with adaptive thr)
#define WWIN 5.0e-4f        // >= 2*delta; delta <= 2.2e-4 (single-product worst case)
#define IDXOFF  (NTOK * DDIM)
#define LOSSOFF (NTOK * DDIM + NTOK)
#define ZPAD 68             // LDS row stride (floats): 68*4=272B = 17*16B, breaks banks

typedef __bf16 bf16x8 __attribute__((ext_vector_type(8)));
typedef float  f32x4  __attribute__((ext_vector_type(4)));

__device__ __forceinline__ float opaque(float x) { asm volatile("" : "+v"(x)); return x; }

// numpy pairwise sum of squares, n=64
__device__ __forceinline__ float np_sumsq64(const float* __restrict__ v) {
    float r[8];
#pragma unroll
    for (int j = 0; j < 8; ++j) r[j] = opaque(v[j] * v[j]);
#pragma unroll
    for (int i = 1; i < 8; ++i)
#pragma unroll
        for (int j = 0; j < 8; ++j) r[j] += opaque(v[8 * i + j] * v[8 * i + j]);
    return ((r[0] + r[1]) + (r[2] + r[3])) + ((r[4] + r[5]) + (r[6] + r[7]));
}

__device__ __forceinline__ unsigned short bf16rne(float x) {
    unsigned u = __float_as_uint(x);
    return (unsigned short)((u + 0x7fffu + ((u >> 16) & 1u)) >> 16);
}

// ---- Prep: exact e2 (np pairwise) + fragment-packed bf16(high) codebook ----
// pfh[tile*128 + kh*64 + lane]: lane = quad*16+l15 holds
//   bf16(e_row[tile*16+l15][quad*8 + kh*32 .. +8])  (16 B = 8 bf16)
__global__ void k_prep(const float* __restrict__ emb, float* __restrict__ e2,
                       uint4* __restrict__ pfh, double* __restrict__ lossacc) {
    int k = blockIdx.x * blockDim.x + threadIdx.x;
    if (k == 0) *lossacc = 0.0;
    if (k >= KCB) return;
    float row[DDIM];
    const float4* r4 = (const float4*)(emb + (size_t)k * DDIM);
#pragma unroll
    for (int i = 0; i < DDIM / 4; ++i) {
        float4 v = r4[i];
        row[4*i+0] = v.x; row[4*i+1] = v.y; row[4*i+2] = v.z; row[4*i+3] = v.w;
    }
    e2[k] = np_sumsq64(row);
    const int tile = k >> 4, rr = k & 15;
#pragma unroll
    for (int q = 0; q < 4; ++q) {
#pragma unroll
        for (int kh = 0; kh < 2; ++kh) {
            union { uint4 v; unsigned short s[8]; } th;
#pragma unroll
            for (int j = 0; j < 8; ++j) th.s[j] = bf16rne(row[q*8 + kh*32 + j]);
            pfh[(size_t)tile * 128 + kh * 64 + q * 16 + rr] = th.v;
        }
    }
}

// ---- Main: R0 structure (best measured) + branch-batched capture + LDS z ----
// 256 thr = 4 waves; wave wn covers a 64-tile quarter for ALL 64 block tokens.
// Occupancy finding (r1-r5): residency ~ floor(256/VGPR) per SIMD; 256-thr
// blocks at VGPR<=64 pack 3-4 blocks/CU; 512-thr blocks strand waves. Keep
// (256,4) which reliably builds at 64 VGPR.
// Sweep: adaptive thresholds (R0 semantics unchanged — capture h <= lagged
// min + W, then thr=min(thr,h+W); LDS atomicMin share every 8 tiles), but
// capture is BRANCH-BATCHED: 32 cmp bits -> one mask32, ONE ballot branch
// per 2-tile pair (R0 had 32 exec-mask branches/tile, serializing tiles).
// Rescore: z rows staged in LDS (padded stride 68), zrow via ds_read_b128,
// erow via float4 — identical FP chain s = fl(fl(z2+e2)-seqFMA(2z*e)).
__global__ __launch_bounds__(256, 4)
void k_vq(const float* __restrict__ z, const float* __restrict__ emb,
          const float* __restrict__ e2g, const uint4* __restrict__ pfh,
          float* __restrict__ out, double* __restrict__ lossacc) {
    __shared__ float z2s[MB];
    __shared__ unsigned v0u[MB];
    __shared__ unsigned long long keys[MB];
    __shared__ unsigned list[LCAP];          // 16 KB
    __shared__ int lcnt;
    __shared__ float red[256];
    __shared__ int bidx_s[MB];
    __shared__ float zrow_s[MB][ZPAD];       // 17 KB staged z block

    const int tid  = threadIdx.x;
    const int lane = tid & 63;
    const int l15  = lane & 15;
    const int quad = lane >> 4;
    const int wn   = tid >> 6;   // 0..3 : 64-tile quarter
    const int tok0 = blockIdx.x * MB;
    const size_t zbase = (size_t)tok0 * DDIM;

    if (tid < MB) { v0u[tid] = 0x7f800000u; keys[tid] = 0xFFFFFFFFFFFFFFFFull; }
    if (tid == 0) lcnt = 0;

    // ---- A-fragments: bf16(-2z), global -> VGPRs (whole-kernel live) ----
    bf16x8 Ah[4][2];   // [ms][kh] — 32 VGPRs
#pragma unroll
    for (int ms = 0; ms < 4; ++ms) {
        const float* p = z + zbase + (size_t)(ms * 16 + l15) * DDIM + quad * 8;
#pragma unroll
        for (int kh = 0; kh < 2; ++kh) {
            float4 u0 = *(const float4*)(p + kh * 32);
            float4 u1 = *(const float4*)(p + kh * 32 + 4);
            float d[8] = {-(u0.x + u0.x), -(u0.y + u0.y), -(u0.z + u0.z), -(u0.w + u0.w),
                          -(u1.x + u1.x), -(u1.y + u1.y), -(u1.z + u1.z), -(u1.w + u1.w)};
            union { bf16x8 v; unsigned short u[8]; } th;
#pragma unroll
            for (int j = 0; j < 8; ++j) th.u[j] = bf16rne(d[j]);
            Ah[ms][kh] = th.v;
        }
    }

    // ---- Stage z block -> LDS (coalesced float4; rows padded to 68) ----
#pragma unroll
    for (int it = 0; it < 4; ++it) {
        int f = it * 256 + tid;              // 0..1023 float4 slots
        int tt = f >> 4, cc = f & 15;
        float4 v = ((const float4*)(z + zbase))[f];
        *(float4*)&zrow_s[tt][cc * 4] = v;
    }
    __syncthreads();   // zrow_s ready (also covers v0u/keys/lcnt init)

    // z2 per token (exact np pairwise) from LDS
    if (tid < MB) {
        float row[DDIM];
#pragma unroll
        for (int i = 0; i < DDIM / 4; ++i) {
            float4 v = *(const float4*)&zrow_s[tid][i * 4];
            row[4*i+0] = v.x; row[4*i+1] = v.y; row[4*i+2] = v.z; row[4*i+3] = v.w;
        }
        z2s[tid] = np_sumsq64(row);
    }

    float thr[16];
#pragma unroll
    for (int i = 0; i < 16; ++i) thr[i] = 3.0e38f;

    const uint4* pbase = pfh + (size_t)(wn * TPW) * 128 + lane;
    const int ncbase = (wn * TPW) * 16 + l15;

    auto commit_reload = [&]() {
#pragma unroll
        for (int i = 0; i < 16; ++i) {
            float v = thr[i] - WWIN;
            v = fminf(v, __shfl_xor(v, 1));
            v = fminf(v, __shfl_xor(v, 2));
            v = fminf(v, __shfl_xor(v, 4));
            v = fminf(v, __shfl_xor(v, 8));
            if (l15 == 0)
                atomicMin(&v0u[(i>>2)*16 + quad*4 + (i&3)], __float_as_uint(v));
        }
#pragma unroll
        for (int i = 0; i < 16; ++i) {
            float g = __uint_as_float(v0u[(i>>2)*16 + quad*4 + (i&3)]);
            thr[i] = fminf(thr[i], g + WWIN);
        }
    };

    // ---- preview (8 tiles, no appends) seeds thresholds block-wide ----
#pragma unroll 1
    for (int t = 0; t < 8; ++t) {
        union { uint4 q; bf16x8 v; } b0, b1;
        b0.q = pbase[(size_t)t * 128]; b1.q = pbase[(size_t)t * 128 + 64];
#pragma unroll
        for (int ms = 0; ms < 4; ++ms) {
            f32x4 a = {0.5f, 0.5f, 0.5f, 0.5f};
            a = __builtin_amdgcn_mfma_f32_16x16x32_bf16(Ah[ms][0], b0.v, a, 0, 0, 0);
            a = __builtin_amdgcn_mfma_f32_16x16x32_bf16(Ah[ms][1], b1.v, a, 0, 0, 0);
#pragma unroll
            for (int r = 0; r < 4; ++r)
                thr[ms*4+r] = fminf(thr[ms*4+r], a[r] + WWIN);
        }
    }
    commit_reload();

    // ---- main sweep: 2 tiles/iter, ONE ballot branch per pair, adaptive ----
    auto compute2 = [&](uint4 p0, uint4 p1, uint4 q0, uint4 q1, int t) {
        unsigned mask = 0;
        {
            union { uint4 q; bf16x8 v; } b0, b1;
            b0.q = p0; b1.q = p1;
#pragma unroll
            for (int ms = 0; ms < 4; ++ms) {
                f32x4 a = {0.5f, 0.5f, 0.5f, 0.5f};
                a = __builtin_amdgcn_mfma_f32_16x16x32_bf16(Ah[ms][0], b0.v, a, 0, 0, 0);
                a = __builtin_amdgcn_mfma_f32_16x16x32_bf16(Ah[ms][1], b1.v, a, 0, 0, 0);
#pragma unroll
                for (int r = 0; r < 4; ++r) {
                    const int i = ms * 4 + r;
                    float h = a[r];
                    mask |= (h <= thr[i]) ? (1u << i) : 0u;
                    thr[i] = fminf(thr[i], h + WWIN);
                }
            }
        }
        {
            union { uint4 q; bf16x8 v; } b0, b1;
            b0.q = q0; b1.q = q1;
#pragma unroll
            for (int ms = 0; ms < 4; ++ms) {
                f32x4 a = {0.5f, 0.5f, 0.5f, 0.5f};
                a = __builtin_amdgcn_mfma_f32_16x16x32_bf16(Ah[ms][0], b0.v, a, 0, 0, 0);
                a = __builtin_amdgcn_mfma_f32_16x16x32_bf16(Ah[ms][1], b1.v, a, 0, 0, 0);
#pragma unroll
                for (int r = 0; r < 4; ++r) {
                    const int i = ms * 4 + r;
                    float h = a[r];
                    mask |= (h <= thr[i]) ? (1u << (16 + i)) : 0u;
                    thr[i] = fminf(thr[i], h + WWIN);
                }
            }
        }
        if (__ballot(mask != 0)) {           // rare; single branch per pair
            while (mask) {
                int b = __builtin_ctz(mask);
                mask &= mask - 1;
                int ts = b >> 4, i = b & 15;
                int m = (i >> 2) * 16 + quad * 4 + (i & 3);
                int ncol = ncbase + (t + ts) * 16;
                int idx = atomicAdd(&lcnt, 1);
                if (idx < LCAP)
                    list[idx] = ((unsigned)m << 12) | (unsigned)ncol;
            }
        }
    };

    uint4 a0 = pbase[0],   a1 = pbase[64];
    uint4 b0 = pbase[128], b1 = pbase[192];
    const uint4* pf = pbase + 256;
#pragma unroll 1
    for (int t = 0; t < TPW; t += 2) {
        uint4 c0 = a0, c1 = a1, d0 = b0, d1 = b1;
        if (t + 2 < TPW) {
            c0 = pf[0]; c1 = pf[64]; d0 = pf[128]; d1 = pf[192];
            pf += 256;
        }
        compute2(a0, a1, b0, b1, t);
        a0 = c0; a1 = c1; b0 = d0; b1 = d1;
        if ((t & 7) == 6 && t + 2 < TPW) commit_reload();
    }
    __syncthreads();   // list complete & visible; z2s visible

    // ---- Exact rescore (np chain), lexicographic (s, n) min per token ----
    // zrow from LDS (b128), erow via float4; FMA order identical to scalar.
    int cnt = lcnt; if (cnt > LCAP) cnt = LCAP;
    for (int i = tid; i < cnt; i += 256) {
        unsigned e = list[i];
        int m = (int)(e >> 12), n = (int)(e & 4095u);
        const float4* er4 = (const float4*)(emb + (size_t)n * DDIM);
        const float4* zr4 = (const float4*)&zrow_s[m][0];
        float a = 0.f;
#pragma unroll
        for (int j4 = 0; j4 < 16; ++j4) {
            float4 ev = er4[j4];
            float4 zv = zr4[j4];
            a = fmaf(zv.x + zv.x, ev.x, a);
            a = fmaf(zv.y + zv.y, ev.y, a);
            a = fmaf(zv.z + zv.z, ev.z, a);
            a = fmaf(zv.w + zv.w, ev.w, a);
        }
        float s = (z2s[m] + e2g[n]) - a;   // two fp32 roundings, exactly as np
        unsigned long long key = ((unsigned long long)__float_as_uint(s) << 32)
                               | (unsigned long long)(unsigned)n;
        atomicMin(&keys[m], key);
    }
    __syncthreads();

    if (tid < MB) {
        int nstar = (int)(keys[tid] & 0xffffffffULL);
        bidx_s[tid] = nstar;
        out[IDXOFF + tok0 + tid] = (float)nstar;
    }
    __syncthreads();

    // ---- Epilogue: quantized gather-write (coalesced float4) + loss ----
    float lsum = 0.f;
#pragma unroll
    for (int it = 0; it < 4; ++it) {
        int f  = it * 256 + tid;    // 0..1023 float4 slots (64 tok * 16)
        int tt = f >> 4, cc = f & 15;
        int idx = bidx_s[tt];
        float4 qv = ((const float4*)(emb + (size_t)idx * DDIM))[cc];
        float4 zv = *(const float4*)&zrow_s[tt][cc * 4];
        ((float4*)(out + zbase))[f] = qv;
        float dx = qv.x - zv.x, dy = qv.y - zv.y;
        float dz = qv.z - zv.z, dw = qv.w - zv.w;
        lsum += dx * dx + dy * dy + dz * dz + dw * dw;
    }
    red[tid] = lsum;
    __syncthreads();
    for (int s = 128; s > 0; s >>= 1) {
        if (tid < s) red[tid] += red[tid + s];
        __syncthreads();
    }
    if (tid == 0) atomicAdd(lossacc, (double)red[0]);
}

__global__ void k_fin(const double* __restrict__ lossacc, float* __restrict__ out) {
    out[LOSSOFF] = (float)(2.0 * (*lossacc) / (double)(NTOK * DDIM));
}

extern "C" void kernel_launch(void* const* d_in, const int* in_sizes, int n_in,
                              void* d_out, int out_size, void* d_ws, size_t ws_size,
                              hipStream_t stream) {
    const float* z   = (const float*)d_in[0];   // [16,4096,64] fp32
    const float* emb = (const float*)d_in[1];   // [4096,64] fp32
    float* out = (float*)d_out;

    char* ws = (char*)d_ws;
    float*  e2g     = (float*)(ws);                 // 16 KB
    uint4*  pfh     = (uint4*)(ws + 16384);         // 512 KB packed high frags
    double* lossacc = (double*)(ws + 16384 + 524288);

    hipLaunchKernelGGL(k_prep, dim3(64), dim3(64), 0, stream, emb, e2g, pfh, lossacc);
    hipLaunchKernelGGL(k_vq, dim3(NTOK / MB), dim3(256), 0, stream,
                       z, emb, e2g, pfh, out, lossacc);
    hipLaunchKernelGGL(k_fin, dim3(1), dim3(1), 0, stream, lossacc, out);
}

// Round 7
// 168.721 us; speedup vs baseline: 1.3886x; 1.0167x over previous
//
#include <hip/hip_runtime.h>

// Problem constants
#define NTOK 65536          // B*S tokens
#define DDIM 64             // embedding dim
#define KCB  4096           // codebook size
#define MB   64             // tokens per block
#define NTILES 256          // 16-col tiles in codebook
#define TPW  64             // tiles per wave (wn quarter: 1024 codes)
#define LCAP 6144           // candidate capacity (~800-1000/block with fixed thr; R5-proven)
#define WWIN 5.0e-4f        // >= 2*delta; delta <= 2.2e-4 (single-product worst case)
#define IDXOFF  (NTOK * DDIM)
#define LOSSOFF (NTOK * DDIM + NTOK)
#define ZPAD 68             // LDS row stride (floats): 68*4=272B, breaks banks

typedef __bf16 bf16x8 __attribute__((ext_vector_type(8)));
typedef float  f32x4  __attribute__((ext_vector_type(4)));

__device__ __forceinline__ float opaque(float x) { asm volatile("" : "+v"(x)); return x; }

// numpy pairwise sum of squares, n=64
__device__ __forceinline__ float np_sumsq64(const float* __restrict__ v) {
    float r[8];
#pragma unroll
    for (int j = 0; j < 8; ++j) r[j] = opaque(v[j] * v[j]);
#pragma unroll
    for (int i = 1; i < 8; ++i)
#pragma unroll
        for (int j = 0; j < 8; ++j) r[j] += opaque(v[8 * i + j] * v[8 * i + j]);
    return ((r[0] + r[1]) + (r[2] + r[3])) + ((r[4] + r[5]) + (r[6] + r[7]));
}

__device__ __forceinline__ unsigned short bf16rne(float x) {
    unsigned u = __float_as_uint(x);
    return (unsigned short)((u + 0x7fffu + ((u >> 16) & 1u)) >> 16);
}

// ---- Prep: exact e2 (np pairwise) + fragment-packed bf16(high) codebook ----
// pfh[tile*128 + kh*64 + lane]: lane = quad*16+l15 holds
//   bf16(e_row[tile*16+l15][quad*8 + kh*32 .. +8])  (16 B = 8 bf16)
__global__ void k_prep(const float* __restrict__ emb, float* __restrict__ e2,
                       uint4* __restrict__ pfh, double* __restrict__ lossacc) {
    int k = blockIdx.x * blockDim.x + threadIdx.x;
    if (k == 0) *lossacc = 0.0;
    if (k >= KCB) return;
    float row[DDIM];
    const float4* r4 = (const float4*)(emb + (size_t)k * DDIM);
#pragma unroll
    for (int i = 0; i < DDIM / 4; ++i) {
        float4 v = r4[i];
        row[4*i+0] = v.x; row[4*i+1] = v.y; row[4*i+2] = v.z; row[4*i+3] = v.w;
    }
    e2[k] = np_sumsq64(row);
    const int tile = k >> 4, rr = k & 15;
#pragma unroll
    for (int q = 0; q < 4; ++q) {
#pragma unroll
        for (int kh = 0; kh < 2; ++kh) {
            union { uint4 v; unsigned short s[8]; } th;
#pragma unroll
            for (int j = 0; j < 8; ++j) th.s[j] = bf16rne(row[q*8 + kh*32 + j]);
            pfh[(size_t)tile * 128 + kh * 64 + q * 16 + rr] = th.v;
        }
    }
}

// ---- Main: fixed-threshold MFMA sweep (R6 shape) + branch-batched capture ----
// 256 thr = 4 waves (shape proven best r0-r6: VGPR=64, ~11-12 waves/CU).
// R6 was VALU-issue-bound (VALUBusy 63%): per-h chain was 5 ops (cmp/cndmask/
// or + add + fmin for adaptive thr). This version FREEZES thr after one
// preview commit (512-code block-wide seed, R5-proven correct superset with
// ~4-8x LCAP margin) -> per-h = cmp+cndmask+or (3 ops), zero in-loop shuffle
// commits. red[] aliased onto dead list[] so LCAP=6144 fits ~43.3KB LDS
// (3 blocks/CU = 12 waves = the measured reg-side pin; no occupancy loss).
// Exact rescore from LDS z: s = fl(fl(z2+e2)-seqFMA(2z*e)) -> lex (s,n).
__global__ __launch_bounds__(256, 4)
void k_vq(const float* __restrict__ z, const float* __restrict__ emb,
          const float* __restrict__ e2g, const uint4* __restrict__ pfh,
          float* __restrict__ out, double* __restrict__ lossacc) {
    __shared__ float z2s[MB];
    __shared__ unsigned v0u[MB];
    __shared__ unsigned long long keys[MB];
    __shared__ unsigned list[LCAP];          // 24 KB; reused as red[] after rescore
    __shared__ int lcnt;
    __shared__ int bidx_s[MB];
    __shared__ float zrow_s[MB][ZPAD];       // 17 KB staged z block

    const int tid  = threadIdx.x;
    const int lane = tid & 63;
    const int l15  = lane & 15;
    const int quad = lane >> 4;
    const int wn   = tid >> 6;   // 0..3 : 64-tile quarter
    const int tok0 = blockIdx.x * MB;
    const size_t zbase = (size_t)tok0 * DDIM;

    if (tid < MB) { v0u[tid] = 0x7f800000u; keys[tid] = 0xFFFFFFFFFFFFFFFFull; }
    if (tid == 0) lcnt = 0;

    // ---- A-fragments: bf16(-2z), global -> VGPRs (whole-kernel live) ----
    bf16x8 Ah[4][2];   // [ms][kh] — 32 VGPRs
#pragma unroll
    for (int ms = 0; ms < 4; ++ms) {
        const float* p = z + zbase + (size_t)(ms * 16 + l15) * DDIM + quad * 8;
#pragma unroll
        for (int kh = 0; kh < 2; ++kh) {
            float4 u0 = *(const float4*)(p + kh * 32);
            float4 u1 = *(const float4*)(p + kh * 32 + 4);
            float d[8] = {-(u0.x + u0.x), -(u0.y + u0.y), -(u0.z + u0.z), -(u0.w + u0.w),
                          -(u1.x + u1.x), -(u1.y + u1.y), -(u1.z + u1.z), -(u1.w + u1.w)};
            union { bf16x8 v; unsigned short u[8]; } th;
#pragma unroll
            for (int j = 0; j < 8; ++j) th.u[j] = bf16rne(d[j]);
            Ah[ms][kh] = th.v;
        }
    }

    // ---- Stage z block -> LDS (coalesced float4; rows padded to 68) ----
#pragma unroll
    for (int it = 0; it < 4; ++it) {
        int f = it * 256 + tid;              // 0..1023 float4 slots
        int tt = f >> 4, cc = f & 15;
        float4 v = ((const float4*)(z + zbase))[f];
        *(float4*)&zrow_s[tt][cc * 4] = v;
    }
    __syncthreads();   // zrow_s ready (also covers v0u/keys/lcnt init)

    // z2 per token (exact np pairwise) from LDS
    if (tid < MB) {
        float row[DDIM];
#pragma unroll
        for (int i = 0; i < DDIM / 4; ++i) {
            float4 v = *(const float4*)&zrow_s[tid][i * 4];
            row[4*i+0] = v.x; row[4*i+1] = v.y; row[4*i+2] = v.z; row[4*i+3] = v.w;
        }
        z2s[tid] = np_sumsq64(row);
    }

    const uint4* pbase = pfh + (size_t)(wn * TPW) * 128 + lane;
    const int ncbase = (wn * TPW) * 16 + l15;

    // ---- preview (8 tiles/wave, 4 waves -> 512-code block seed), raw min ----
    float rm[16];
#pragma unroll
    for (int i = 0; i < 16; ++i) rm[i] = 3.0e38f;
#pragma unroll 1
    for (int t = 0; t < 8; ++t) {
        union { uint4 q; bf16x8 v; } b0, b1;
        b0.q = pbase[(size_t)t * 128]; b1.q = pbase[(size_t)t * 128 + 64];
#pragma unroll
        for (int ms = 0; ms < 4; ++ms) {
            f32x4 a = {0.5f, 0.5f, 0.5f, 0.5f};
            a = __builtin_amdgcn_mfma_f32_16x16x32_bf16(Ah[ms][0], b0.v, a, 0, 0, 0);
            a = __builtin_amdgcn_mfma_f32_16x16x32_bf16(Ah[ms][1], b1.v, a, 0, 0, 0);
#pragma unroll
            for (int r = 0; r < 4; ++r) rm[ms*4+r] = fminf(rm[ms*4+r], a[r]);
        }
    }
    // commit raw mins (16-lane group reduce -> block atomicMin)
#pragma unroll
    for (int i = 0; i < 16; ++i) {
        float v = rm[i];
        v = fminf(v, __shfl_xor(v, 1));
        v = fminf(v, __shfl_xor(v, 2));
        v = fminf(v, __shfl_xor(v, 4));
        v = fminf(v, __shfl_xor(v, 8));
        if (l15 == 0)
            atomicMin(&v0u[(i >> 2) * 16 + quad * 4 + (i & 3)], __float_as_uint(v));
    }
    __syncthreads();   // v0u complete block-wide; z2s visible

    float thr[16];     // FIXED for the whole sweep: block 512-code min + W
#pragma unroll
    for (int i = 0; i < 16; ++i)
        thr[i] = __uint_as_float(v0u[(i >> 2) * 16 + quad * 4 + (i & 3)]) + WWIN;

    // ---- main sweep: 2 tiles/iter, fixed thr, one branch region per pair ----
    auto compute2 = [&](uint4 p0, uint4 p1, uint4 q0, uint4 q1, int t) {
        unsigned mask = 0;
        {
            union { uint4 q; bf16x8 v; } b0, b1;
            b0.q = p0; b1.q = p1;
#pragma unroll
            for (int ms = 0; ms < 4; ++ms) {
                f32x4 a = {0.5f, 0.5f, 0.5f, 0.5f};
                a = __builtin_amdgcn_mfma_f32_16x16x32_bf16(Ah[ms][0], b0.v, a, 0, 0, 0);
                a = __builtin_amdgcn_mfma_f32_16x16x32_bf16(Ah[ms][1], b1.v, a, 0, 0, 0);
#pragma unroll
                for (int r = 0; r < 4; ++r) {
                    const int i = ms * 4 + r;
                    mask |= (a[r] <= thr[i]) ? (1u << i) : 0u;
                }
            }
        }
        {
            union { uint4 q; bf16x8 v; } b0, b1;
            b0.q = q0; b1.q = q1;
#pragma unroll
            for (int ms = 0; ms < 4; ++ms) {
                f32x4 a = {0.5f, 0.5f, 0.5f, 0.5f};
                a = __builtin_amdgcn_mfma_f32_16x16x32_bf16(Ah[ms][0], b0.v, a, 0, 0, 0);
                a = __builtin_amdgcn_mfma_f32_16x16x32_bf16(Ah[ms][1], b1.v, a, 0, 0, 0);
#pragma unroll
                for (int r = 0; r < 4; ++r) {
                    const int i = ms * 4 + r;
                    mask |= (a[r] <= thr[i]) ? (1u << (16 + i)) : 0u;
                }
            }
        }
        while (mask) {                        // exec-masked; skipped when empty
            int b = __builtin_ctz(mask);
            mask &= mask - 1;
            int ts = b >> 4, i = b & 15;
            int m = (i >> 2) * 16 + quad * 4 + (i & 3);
            int ncol = ncbase + (t + ts) * 16;
            int idx = atomicAdd(&lcnt, 1);
            if (idx < LCAP)
                list[idx] = ((unsigned)m << 12) | (unsigned)ncol;
        }
    };

    uint4 a0 = pbase[0],   a1 = pbase[64];
    uint4 b0 = pbase[128], b1 = pbase[192];
    const uint4* pf = pbase + 256;
#pragma unroll 1
    for (int t = 0; t < TPW; t += 2) {
        uint4 c0 = a0, c1 = a1, d0 = b0, d1 = b1;
        if (t + 2 < TPW) {
            c0 = pf[0]; c1 = pf[64]; d0 = pf[128]; d1 = pf[192];
            pf += 256;
        }
        compute2(a0, a1, b0, b1, t);
        a0 = c0; a1 = c1; b0 = d0; b1 = d1;
    }
    __syncthreads();   // list complete & visible

    // ---- Exact rescore (np chain), lexicographic (s, n) min per token ----
    // zrow from LDS (b128), erow via float4; FMA order identical to scalar.
    int cnt = lcnt; if (cnt > LCAP) cnt = LCAP;
    for (int i = tid; i < cnt; i += 256) {
        unsigned e = list[i];
        int m = (int)(e >> 12), n = (int)(e & 4095u);
        const float4* er4 = (const float4*)(emb + (size_t)n * DDIM);
        const float4* zr4 = (const float4*)&zrow_s[m][0];
        float a = 0.f;
#pragma unroll
        for (int j4 = 0; j4 < 16; ++j4) {
            float4 ev = er4[j4];
            float4 zv = zr4[j4];
            a = fmaf(zv.x + zv.x, ev.x, a);
            a = fmaf(zv.y + zv.y, ev.y, a);
            a = fmaf(zv.z + zv.z, ev.z, a);
            a = fmaf(zv.w + zv.w, ev.w, a);
        }
        float s = (z2s[m] + e2g[n]) - a;   // two fp32 roundings, exactly as np
        unsigned long long key = ((unsigned long long)__float_as_uint(s) << 32)
                               | (unsigned long long)(unsigned)n;
        atomicMin(&keys[m], key);
    }
    __syncthreads();

    if (tid < MB) {
        int nstar = (int)(keys[tid] & 0xffffffffULL);
        bidx_s[tid] = nstar;
        out[IDXOFF + tok0 + tid] = (float)nstar;
    }
    __syncthreads();

    // ---- Epilogue: quantized gather-write (coalesced float4) + loss ----
    float* red = (float*)list;    // list is dead past the rescore barrier
    float lsum = 0.f;
#pragma unroll
    for (int it = 0; it < 4; ++it) {
        int f  = it * 256 + tid;    // 0..1023 float4 slots (64 tok * 16)
        int tt = f >> 4, cc = f & 15;
        int idx = bidx_s[tt];
        float4 qv = ((const float4*)(emb + (size_t)idx * DDIM))[cc];
        float4 zv = *(const float4*)&zrow_s[tt][cc * 4];
        ((float4*)(out + zbase))[f] = qv;
        float dx = qv.x - zv.x, dy = qv.y - zv.y;
        float dz = qv.z - zv.z, dw = qv.w - zv.w;
        lsum += dx * dx + dy * dy + dz * dz + dw * dw;
    }
    red[tid] = lsum;
    __syncthreads();
    for (int s = 128; s > 0; s >>= 1) {
        if (tid < s) red[tid] += red[tid + s];
        __syncthreads();
    }
    if (tid == 0) atomicAdd(lossacc, (double)red[0]);
}

__global__ void k_fin(const double* __restrict__ lossacc, float* __restrict__ out) {
    out[LOSSOFF] = (float)(2.0 * (*lossacc) / (double)(NTOK * DDIM));
}

extern "C" void kernel_launch(void* const* d_in, const int* in_sizes, int n_in,
                              void* d_out, int out_size, void* d_ws, size_t ws_size,
                              hipStream_t stream) {
    const float* z   = (const float*)d_in[0];   // [16,4096,64] fp32
    const float* emb = (const float*)d_in[1];   // [4096,64] fp32
    float* out = (float*)d_out;

    char* ws = (char*)d_ws;
    float*  e2g     = (float*)(ws);                 // 16 KB
    uint4*  pfh     = (uint4*)(ws + 16384);         // 512 KB packed high frags
    double* lossacc = (double*)(ws + 16384 + 524288);

    hipLaunchKernelGGL(k_prep, dim3(64), dim3(64), 0, stream, emb, e2g, pfh, lossacc);
    hipLaunchKernelGGL(k_vq, dim3(NTOK / MB), dim3(256), 0, stream,
                       z, emb, e2g, pfh, out, lossacc);
    hipLaunchKernelGGL(k_fin, dim3(1), dim3(1), 0, stream, lossacc, out);
}

// Round 8
// 156.589 us; speedup vs baseline: 1.4962x; 1.0775x over previous
//
#include <hip/hip_runtime.h>

// Problem constants
#define NTOK 65536          // B*S tokens
#define DDIM 64             // embedding dim
#define KCB  4096           // codebook size
#define MB   64             // tokens per block
#define NTILES 256          // 16-col tiles in codebook
#define TPW  128            // tiles per wave (half codebook; 2 waves share a half)
#define LCAP 4096           // candidate capacity (~1000/block; exhaustive fallback on overflow)
#define WWIN 5.0e-4f        // >= 2*delta; delta <= 2.2e-4 (single-product worst case)
#define IDXOFF  (NTOK * DDIM)
#define LOSSOFF (NTOK * DDIM + NTOK)
#define ZPAD 68             // LDS row stride (floats): 272B, 16B-aligned, breaks banks

typedef __bf16 bf16x8 __attribute__((ext_vector_type(8)));
typedef float  f32x4  __attribute__((ext_vector_type(4)));

__device__ __forceinline__ float opaque(float x) { asm volatile("" : "+v"(x)); return x; }

// numpy pairwise sum of squares, n=64
__device__ __forceinline__ float np_sumsq64(const float* __restrict__ v) {
    float r[8];
#pragma unroll
    for (int j = 0; j < 8; ++j) r[j] = opaque(v[j] * v[j]);
#pragma unroll
    for (int i = 1; i < 8; ++i)
#pragma unroll
        for (int j = 0; j < 8; ++j) r[j] += opaque(v[8 * i + j] * v[8 * i + j]);
    return ((r[0] + r[1]) + (r[2] + r[3])) + ((r[4] + r[5]) + (r[6] + r[7]));
}

__device__ __forceinline__ unsigned short bf16rne(float x) {
    unsigned u = __float_as_uint(x);
    return (unsigned short)((u + 0x7fffu + ((u >> 16) & 1u)) >> 16);
}

// ---- Prep: exact e2 (np pairwise) + fragment-packed bf16(high) codebook ----
// pfh[tile*128 + kh*64 + lane]: lane = quad*16+l15 holds
//   bf16(e_row[tile*16+l15][quad*8 + kh*32 .. +8])  (16 B = 8 bf16)
__global__ void k_prep(const float* __restrict__ emb, float* __restrict__ e2,
                       uint4* __restrict__ pfh, double* __restrict__ lossacc) {
    int k = blockIdx.x * blockDim.x + threadIdx.x;
    if (k == 0) *lossacc = 0.0;
    if (k >= KCB) return;
    float row[DDIM];
    const float4* r4 = (const float4*)(emb + (size_t)k * DDIM);
#pragma unroll
    for (int i = 0; i < DDIM / 4; ++i) {
        float4 v = r4[i];
        row[4*i+0] = v.x; row[4*i+1] = v.y; row[4*i+2] = v.z; row[4*i+3] = v.w;
    }
    e2[k] = np_sumsq64(row);
    const int tile = k >> 4, rr = k & 15;
#pragma unroll
    for (int q = 0; q < 4; ++q) {
#pragma unroll
        for (int kh = 0; kh < 2; ++kh) {
            union { uint4 v; unsigned short s[8]; } th;
#pragma unroll
            for (int j = 0; j < 8; ++j) th.s[j] = bf16rne(row[q*8 + kh*32 + j]);
            pfh[(size_t)tile * 128 + kh * 64 + q * 16 + rr] = th.v;
        }
    }
}

// ---- Main: fixed-thr MFMA sweep, 32-token x half-codebook waves ----
// Register cliffs measured r0-r7: <=64 VGPR -> 4 waves/SIMD, <=80 -> 3,
// <=88 -> 2 (effective 256-reg/SIMD budget, granule 8). R7's 64-token wave
// needed Ah32+thr16+bufs32 = 84 regs -> 2 waves/SIMD. This remap: wave
// (g,hh) = (wn>>1, wn&1) owns tokens [g*32, g*32+32) over tile half
// [hh*128, +128): Ah[2][2]=16, thr[8]=8, bufs 32 -> ~60 regs -> 4 waves/SIMD.
// Same per-wave MFMA (576) and VALU; pfh L2 traffic 2x (1 MB/block, ~9 TB/s
// aggregate vs 34 TB/s L2 peak — cheap). Preview 16 tiles/wave keeps the
// block-wide threshold seed at exactly 512 codes/token (2 waves x 256).
// thr FIXED after preview commit (superset guarantee; R5/R7-proven).
// LCAP 4096 (LDS 34.9K -> 4 blocks/CU) + exhaustive fallback if lcnt>LCAP
// (correctness insurance, ~never taken).
// Exact rescore from LDS z: s = fl(fl(z2+e2)-seqFMA(2z*e)) -> lex (s,n).
__global__ __launch_bounds__(256, 4)
void k_vq(const float* __restrict__ z, const float* __restrict__ emb,
          const float* __restrict__ e2g, const uint4* __restrict__ pfh,
          float* __restrict__ out, double* __restrict__ lossacc) {
    __shared__ float z2s[MB];
    __shared__ unsigned v0u[MB];
    __shared__ unsigned long long keys[MB];
    __shared__ unsigned list[LCAP];          // 16 KB; reused as red[] after rescore
    __shared__ int lcnt;
    __shared__ int bidx_s[MB];
    __shared__ float zrow_s[MB][ZPAD];       // 17 KB staged z block

    const int tid  = threadIdx.x;
    const int lane = tid & 63;
    const int l15  = lane & 15;
    const int quad = lane >> 4;
    const int wn   = tid >> 6;
    const int g    = wn >> 1;    // token half: tokens [g*32, g*32+32)
    const int hh   = wn & 1;     // tile half: tiles [hh*128, hh*128+128)
    const int tok0 = blockIdx.x * MB;
    const size_t zbase = (size_t)tok0 * DDIM;

    if (tid < MB) { v0u[tid] = 0x7f800000u; keys[tid] = 0xFFFFFFFFFFFFFFFFull; }
    if (tid == 0) lcnt = 0;

    // ---- A-fragments: bf16(-2z) for this wave's 32 tokens — 16 VGPRs ----
    bf16x8 Ah[2][2];   // [ms_local][kh]
#pragma unroll
    for (int ms = 0; ms < 2; ++ms) {
        const float* p = z + zbase + (size_t)((2 * g + ms) * 16 + l15) * DDIM + quad * 8;
#pragma unroll
        for (int kh = 0; kh < 2; ++kh) {
            float4 u0 = *(const float4*)(p + kh * 32);
            float4 u1 = *(const float4*)(p + kh * 32 + 4);
            float d[8] = {-(u0.x + u0.x), -(u0.y + u0.y), -(u0.z + u0.z), -(u0.w + u0.w),
                          -(u1.x + u1.x), -(u1.y + u1.y), -(u1.z + u1.z), -(u1.w + u1.w)};
            union { bf16x8 v; unsigned short u[8]; } th;
#pragma unroll
            for (int j = 0; j < 8; ++j) th.u[j] = bf16rne(d[j]);
            Ah[ms][kh] = th.v;
        }
    }

    // ---- Stage z block -> LDS (coalesced float4; rows padded to 68) ----
#pragma unroll
    for (int it = 0; it < 4; ++it) {
        int f = it * 256 + tid;              // 0..1023 float4 slots
        int tt = f >> 4, cc = f & 15;
        float4 v = ((const float4*)(z + zbase))[f];
        *(float4*)&zrow_s[tt][cc * 4] = v;
    }
    __syncthreads();   // zrow_s ready (also covers v0u/keys/lcnt init)

    // z2 per token (exact np pairwise) from LDS
    if (tid < MB) {
        float row[DDIM];
#pragma unroll
        for (int i = 0; i < DDIM / 4; ++i) {
            float4 v = *(const float4*)&zrow_s[tid][i * 4];
            row[4*i+0] = v.x; row[4*i+1] = v.y; row[4*i+2] = v.z; row[4*i+3] = v.w;
        }
        z2s[tid] = np_sumsq64(row);
    }

    const uint4* pbase = pfh + (size_t)hh * 128 * 128 + lane;
    const int ncbase = hh * 128 * 16 + l15;

    // ---- preview (16 tiles/wave; 2 waves/token-half -> 512-code seed) ----
    float rm[8];
#pragma unroll
    for (int i = 0; i < 8; ++i) rm[i] = 3.0e38f;
#pragma unroll 1
    for (int t = 0; t < 16; ++t) {
        union { uint4 q; bf16x8 v; } b0, b1;
        b0.q = pbase[(size_t)t * 128]; b1.q = pbase[(size_t)t * 128 + 64];
#pragma unroll
        for (int ms = 0; ms < 2; ++ms) {
            f32x4 a = {0.5f, 0.5f, 0.5f, 0.5f};
            a = __builtin_amdgcn_mfma_f32_16x16x32_bf16(Ah[ms][0], b0.v, a, 0, 0, 0);
            a = __builtin_amdgcn_mfma_f32_16x16x32_bf16(Ah[ms][1], b1.v, a, 0, 0, 0);
#pragma unroll
            for (int r = 0; r < 4; ++r) rm[ms*4+r] = fminf(rm[ms*4+r], a[r]);
        }
    }
    // commit raw mins (16-lane group reduce -> block atomicMin)
#pragma unroll
    for (int i = 0; i < 8; ++i) {
        float v = rm[i];
        v = fminf(v, __shfl_xor(v, 1));
        v = fminf(v, __shfl_xor(v, 2));
        v = fminf(v, __shfl_xor(v, 4));
        v = fminf(v, __shfl_xor(v, 8));
        if (l15 == 0)
            atomicMin(&v0u[(2*g + (i>>2)) * 16 + quad*4 + (i&3)], __float_as_uint(v));
    }
    __syncthreads();   // v0u complete block-wide

    float thr[8];      // FIXED for the whole sweep: block 512-code min + W
#pragma unroll
    for (int i = 0; i < 8; ++i)
        thr[i] = __uint_as_float(v0u[(2*g + (i>>2)) * 16 + quad*4 + (i&3)]) + WWIN;

    // ---- main sweep: 2 tiles/iter, fixed thr, one branch region per pair ----
    auto compute2 = [&](uint4 p0, uint4 p1, uint4 q0, uint4 q1, int t) {
        unsigned mask = 0;
        {
            union { uint4 q; bf16x8 v; } b0, b1;
            b0.q = p0; b1.q = p1;
#pragma unroll
            for (int ms = 0; ms < 2; ++ms) {
                f32x4 a = {0.5f, 0.5f, 0.5f, 0.5f};
                a = __builtin_amdgcn_mfma_f32_16x16x32_bf16(Ah[ms][0], b0.v, a, 0, 0, 0);
                a = __builtin_amdgcn_mfma_f32_16x16x32_bf16(Ah[ms][1], b1.v, a, 0, 0, 0);
#pragma unroll
                for (int r = 0; r < 4; ++r)
                    mask |= (a[r] <= thr[ms*4+r]) ? (1u << (ms*4+r)) : 0u;
            }
        }
        {
            union { uint4 q; bf16x8 v; } b0, b1;
            b0.q = q0; b1.q = q1;
#pragma unroll
            for (int ms = 0; ms < 2; ++ms) {
                f32x4 a = {0.5f, 0.5f, 0.5f, 0.5f};
                a = __builtin_amdgcn_mfma_f32_16x16x32_bf16(Ah[ms][0], b0.v, a, 0, 0, 0);
                a = __builtin_amdgcn_mfma_f32_16x16x32_bf16(Ah[ms][1], b1.v, a, 0, 0, 0);
#pragma unroll
                for (int r = 0; r < 4; ++r)
                    mask |= (a[r] <= thr[ms*4+r]) ? (1u << (8 + ms*4+r)) : 0u;
            }
        }
        while (mask) {                        // exec-masked; skipped when empty
            int b = __builtin_ctz(mask);
            mask &= mask - 1;
            int ts = b >> 3, i = b & 7;
            int m = (2*g + (i >> 2)) * 16 + quad * 4 + (i & 3);
            int ncol = ncbase + (t + ts) * 16;
            int idx = atomicAdd(&lcnt, 1);
            if (idx < LCAP)
                list[idx] = ((unsigned)m << 12) | (unsigned)ncol;
        }
    };

    uint4 a0 = pbase[0],   a1 = pbase[64];
    uint4 b0 = pbase[128], b1 = pbase[192];
    const uint4* pf = pbase + 256;
#pragma unroll 1
    for (int t = 0; t < TPW; t += 2) {
        uint4 c0 = a0, c1 = a1, d0 = b0, d1 = b1;
        if (t + 2 < TPW) {
            c0 = pf[0]; c1 = pf[64]; d0 = pf[128]; d1 = pf[192];
            pf += 256;
        }
        compute2(a0, a1, b0, b1, t);
        a0 = c0; a1 = c1; b0 = d0; b1 = d1;
    }
    __syncthreads();   // list complete & visible

    // ---- Exact rescore (np chain), lexicographic (s, n) min per token ----
    int cnt = lcnt;
    if (cnt <= LCAP) {
        for (int i = tid; i < cnt; i += 256) {
            unsigned e = list[i];
            int m = (int)(e >> 12), n = (int)(e & 4095u);
            const float4* er4 = (const float4*)(emb + (size_t)n * DDIM);
            const float4* zr4 = (const float4*)&zrow_s[m][0];
            float a = 0.f;
#pragma unroll
            for (int j4 = 0; j4 < 16; ++j4) {
                float4 ev = er4[j4];
                float4 zv = zr4[j4];
                a = fmaf(zv.x + zv.x, ev.x, a);
                a = fmaf(zv.y + zv.y, ev.y, a);
                a = fmaf(zv.z + zv.z, ev.z, a);
                a = fmaf(zv.w + zv.w, ev.w, a);
            }
            float s = (z2s[m] + e2g[n]) - a;   // two fp32 roundings, exactly as np
            unsigned long long key = ((unsigned long long)__float_as_uint(s) << 32)
                                   | (unsigned long long)(unsigned)n;
            atomicMin(&keys[m], key);
        }
    } else {
        // overflow fallback: exhaustive exact rescore (correctness insurance)
        for (int i = tid; i < MB * KCB; i += 256) {
            int m = i >> 12, n = i & 4095;
            const float4* er4 = (const float4*)(emb + (size_t)n * DDIM);
            const float4* zr4 = (const float4*)&zrow_s[m][0];
            float a = 0.f;
#pragma unroll
            for (int j4 = 0; j4 < 16; ++j4) {
                float4 ev = er4[j4];
                float4 zv = zr4[j4];
                a = fmaf(zv.x + zv.x, ev.x, a);
                a = fmaf(zv.y + zv.y, ev.y, a);
                a = fmaf(zv.z + zv.z, ev.z, a);
                a = fmaf(zv.w + zv.w, ev.w, a);
            }
            float s = (z2s[m] + e2g[n]) - a;
            unsigned long long key = ((unsigned long long)__float_as_uint(s) << 32)
                                   | (unsigned long long)(unsigned)n;
            atomicMin(&keys[m], key);
        }
    }
    __syncthreads();

    if (tid < MB) {
        int nstar = (int)(keys[tid] & 0xffffffffULL);
        bidx_s[tid] = nstar;
        out[IDXOFF + tok0 + tid] = (float)nstar;
    }
    __syncthreads();

    // ---- Epilogue: quantized gather-write (coalesced float4) + loss ----
    float* red = (float*)list;    // list is dead past the rescore barrier
    float lsum = 0.f;
#pragma unroll
    for (int it = 0; it < 4; ++it) {
        int f  = it * 256 + tid;    // 0..1023 float4 slots (64 tok * 16)
        int tt = f >> 4, cc = f & 15;
        int idx = bidx_s[tt];
        float4 qv = ((const float4*)(emb + (size_t)idx * DDIM))[cc];
        float4 zv = *(const float4*)&zrow_s[tt][cc * 4];
        ((float4*)(out + zbase))[f] = qv;
        float dx = qv.x - zv.x, dy = qv.y - zv.y;
        float dz = qv.z - zv.z, dw = qv.w - zv.w;
        lsum += dx * dx + dy * dy + dz * dz + dw * dw;
    }
    red[tid] = lsum;
    __syncthreads();
    for (int s = 128; s > 0; s >>= 1) {
        if (tid < s) red[tid] += red[tid + s];
        __syncthreads();
    }
    if (tid == 0) atomicAdd(lossacc, (double)red[0]);
}

__global__ void k_fin(const double* __restrict__ lossacc, float* __restrict__ out) {
    out[LOSSOFF] = (float)(2.0 * (*lossacc) / (double)(NTOK * DDIM));
}

extern "C" void kernel_launch(void* const* d_in, const int* in_sizes, int n_in,
                              void* d_out, int out_size, void* d_ws, size_t ws_size,
                              hipStream_t stream) {
    const float* z   = (const float*)d_in[0];   // [16,4096,64] fp32
    const float* emb = (const float*)d_in[1];   // [4096,64] fp32
    float* out = (float*)d_out;

    char* ws = (char*)d_ws;
    float*  e2g     = (float*)(ws);                 // 16 KB
    uint4*  pfh     = (uint4*)(ws + 16384);         // 512 KB packed high frags
    double* lossacc = (double*)(ws + 16384 + 524288);

    hipLaunchKernelGGL(k_prep, dim3(64), dim3(64), 0, stream, emb, e2g, pfh, lossacc);
    hipLaunchKernelGGL(k_vq, dim3(NTOK / MB), dim3(256), 0, stream,
                       z, emb, e2g, pfh, out, lossacc);
    hipLaunchKernelGGL(k_fin, dim3(1), dim3(1), 0, stream, lossacc, out);
}